// Round 22
// baseline (130.532 us; speedup 1.0000x reference)
//
#include <hip/hip_runtime.h>
#include <hip/hip_bf16.h>

typedef __hip_bfloat16 bf16;
typedef __attribute__((ext_vector_type(8))) __bf16 bf16x8;
typedef __attribute__((ext_vector_type(4))) __bf16 bf16x4;
typedef __attribute__((ext_vector_type(4))) float f32x4;
typedef unsigned short u16;

#define MFMA16(a, b, c) __builtin_amdgcn_mfma_f32_16x16x32_bf16((a), (b), (c), 0, 0, 0)

static constexpr int B_ = 2, T_ = 2048, C_ = 1024, H_ = 16, D_ = 64;
static constexpr int BT = B_ * T_;   // 4096
static constexpr int N3 = 3 * C_;    // 3072

__device__ __forceinline__ void gload16(void* lds, const void* g) {
    __builtin_amdgcn_global_load_lds(
        (const __attribute__((address_space(1))) unsigned int*)g,
        (__attribute__((address_space(3))) unsigned int*)lds, 16, 0, 0);
}

__device__ __forceinline__ u16 bb(float x) {
    return __builtin_bit_cast(u16, __float2bfloat16(x));
}

// ---------- fused prep kernel: transpose Wqkv | transpose Wproj | convert x | rope ----
__global__ __launch_bounds__(256) void k_prep(
    const float* __restrict__ Wqkv, const float* __restrict__ Wproj,
    const float* __restrict__ x,
    bf16* __restrict__ wqkvT, bf16* __restrict__ wprojT, bf16* __restrict__ xb,
    float* __restrict__ ct, float* __restrict__ st) {
    __shared__ float t[32][33];
    const int id = blockIdx.x;
    const int tid = threadIdx.x;
    if (id < 4096) {
        const float* src;
        bf16* dst;
        int N, bx, by;
        if (id < 3072) {
            src = Wqkv; dst = wqkvT; N = N3;
            bx = (id % 96) * 32; by = (id / 96) * 32;
        } else {
            src = Wproj; dst = wprojT; N = C_;
            int u = id - 3072;
            bx = (u % 32) * 32; by = (u / 32) * 32;
        }
        int tx = tid & 31, ty = tid >> 5;
#pragma unroll
        for (int i = 0; i < 32; i += 8)
            t[ty + i][tx] = src[(size_t)(by + ty + i) * N + bx + tx];
        __syncthreads();
#pragma unroll
        for (int i = 0; i < 32; i += 8)
            dst[(size_t)(bx + ty + i) * 1024 + by + tx] = __float2bfloat16(t[tx][ty + i]);
    } else if (id < 8192) {
        int i = (id - 4096) * 256 + tid;          // float4 index
        float4 v = reinterpret_cast<const float4*>(x)[i];
        xb[4 * i + 0] = __float2bfloat16(v.x);
        xb[4 * i + 1] = __float2bfloat16(v.y);
        xb[4 * i + 2] = __float2bfloat16(v.z);
        xb[4 * i + 3] = __float2bfloat16(v.w);
    } else {
        int i = (id - 8192) * 256 + tid;          // t*32 + f
        int tt = i >> 5, f = i & 31;
        float invf = exp2f(-(float)f * 0.4152410118609203f);  // 10000^(-f/32)
        float ang = (float)tt * invf;
        ct[i] = cosf(ang);
        st[i] = sinf(ang);
    }
}

// ---------- QKV GEMM: R18 pipeline + XCD-aware block remap (T1) ----------
// id&7 == XCD (round-robin dispatch). XCD x owns N-cols {3x,3x+1,3x+2} for ALL
// 32 M-rows: B slab (0.75 MB) L2-resident; A read once through L3. Bijective:
// 768 = 8 XCD x (3 N x 32 M).
__global__ __launch_bounds__(256) void k_gemm_qkv(
    const bf16* __restrict__ A, const bf16* __restrict__ Bt,
    const float* __restrict__ bias,
    const float* __restrict__ ct, const float* __restrict__ st,
    bf16* __restrict__ q, bf16* __restrict__ kk, bf16* __restrict__ vt) {
    __shared__ bf16 lA[3][128 * 32];
    __shared__ bf16 lB[3][128 * 32];
    const int tid = threadIdx.x;
    const int wave = tid >> 6, lane = tid & 63;
    const int wm = wave >> 1, wn = wave & 1;
    const int l16 = lane & 15, lg = lane >> 4;
    const int id = blockIdx.x;
    const int xcd = id & 7, kk2 = id >> 3;
    const int n0 = (xcd * 3 + (kk2 % 3)) * 128;
    const int m0 = (kk2 / 3) * 128;

    f32x4 acc[4][4];
#pragma unroll
    for (int i = 0; i < 4; i++)
#pragma unroll
        for (int j = 0; j < 4; j++) acc[i][j] = (f32x4){0.f, 0.f, 0.f, 0.f};

    const int r = lane >> 2;
    const int sc = (lane & 3) ^ (r & 3);
    const bf16* gA = A + (size_t)(m0 + wave * 32 + r) * 1024 + sc * 8;
    const bf16* gB = Bt + (size_t)(n0 + wave * 32 + r) * 1024 + sc * 8;
    const int sw = (lg ^ (l16 & 3)) * 8;

    auto stage = [&](int buf, int k0) {
        bf16* sA = lA[buf] + wave * 1024;
        bf16* sB = lB[buf] + wave * 1024;
        gload16(sA, gA + k0);
        gload16(sA + 512, gA + (size_t)16 * 1024 + k0);
        gload16(sB, gB + k0);
        gload16(sB + 512, gB + (size_t)16 * 1024 + k0);
    };
    auto compute = [&](int buf) {
        bf16x8 af[4], bfr[4];
#pragma unroll
        for (int mi = 0; mi < 4; mi++)
            af[mi] = *(const bf16x8*)(lA[buf] + (wm * 64 + mi * 16 + l16) * 32 + sw);
#pragma unroll
        for (int nj = 0; nj < 4; nj++)
            bfr[nj] = *(const bf16x8*)(lB[buf] + (wn * 64 + nj * 16 + l16) * 32 + sw);
#pragma unroll
        for (int mi = 0; mi < 4; mi++)
#pragma unroll
            for (int nj = 0; nj < 4; nj++)
                acc[mi][nj] = MFMA16(af[mi], bfr[nj], acc[mi][nj]);
    };

    stage(0, 0);
    stage(1, 32);
    int buf = 0;
    for (int k0 = 0; k0 < 992; k0 += 32) {
        asm volatile("s_waitcnt vmcnt(4)" ::: "memory");
        __builtin_amdgcn_s_barrier();
        __builtin_amdgcn_sched_barrier(0);
        if (k0 + 64 < 1024) {
            int nb = buf + 2; if (nb >= 3) nb -= 3;
            stage(nb, k0 + 64);
        }
        compute(buf);
        buf = (buf == 2) ? 0 : buf + 1;
    }
    asm volatile("s_waitcnt vmcnt(0)" ::: "memory");
    __builtin_amdgcn_s_barrier();
    __builtin_amdgcn_sched_barrier(0);
    compute(buf);

    // epilogue: bias + RoPE + scatter
    const int b = m0 >> 11;
#pragma unroll
    for (int mi = 0; mi < 4; mi++) {
        int mbase = m0 + wm * 64 + mi * 16 + lg * 4;
#pragma unroll
        for (int nj = 0; nj < 4; nj++) {
            int n = n0 + wn * 64 + nj * 16 + l16;
            int which = n >> 10;
            int nq = n & 1023;
            int h = nq >> 6, d = nq & 63;
#pragma unroll
            for (int rr = 0; rr < 4; rr++) {
                int m = mbase + rr;
                int t = m & 2047;
                float v = acc[mi][nj][rr] + bias[n];
                if (which == 2) {
                    vt[((size_t)(b * 16 + h) * 64 + d) * 2048 + t] = __float2bfloat16(v);
                } else {
                    float pv = acc[mi][nj ^ 2][rr] + bias[n ^ 32];
                    float c = ct[t * 32 + (d & 31)];
                    float s = st[t * 32 + (d & 31)];
                    float rh = (d < 32) ? -pv : pv;
                    float o = v * c + rh * s;
                    bf16* dst = (which == 0) ? q : kk;
                    dst[((size_t)(b * 16 + h) * 2048 + t) * 64 + d] = __float2bfloat16(o);
                }
            }
        }
    }
}

// ---------- flash attention: split-K + counted-vmcnt pipeline (R21) ----------
__global__ __launch_bounds__(256, 3) void k_attn(
    const bf16* __restrict__ qg, const bf16* __restrict__ kg,
    const bf16* __restrict__ vtg, bf16* __restrict__ y) {
    __shared__ bf16 smem[2][3][4096];       // [pair][buf][K 2048 | V 2048] = 48 KB
    const int wv = threadIdx.x >> 6;
    const int pair = wv >> 1, qh = wv & 1;
    const int lane = threadIdx.x & 63;
    const int l16 = lane & 15, lg = lane >> 4;
    const int id = blockIdx.x;
    const int bh = id & 31;                 // id%8==bh%8 pins head to one XCD
    const int s = 31 - (id >> 5);           // strip (heavy first)
    const int q0w = s * 64 + 32 * qh;       // this wave's 32 q-rows
    const bf16* qh_p = qg + (size_t)bh * (2048 * 64);
    const bf16* kh = kg + (size_t)bh * (2048 * 64);
    const bf16* vh = vtg + (size_t)bh * (64 * 2048);

    bf16x8 qf[2][2];
#pragma unroll
    for (int g = 0; g < 2; g++)
#pragma unroll
        for (int h = 0; h < 2; h++)
            qf[g][h] = *(const bf16x8*)(qh_p + (size_t)(q0w + 16 * g + l16) * 64 + 32 * h + 8 * lg);

    f32x4 o[2][4];
#pragma unroll
    for (int g = 0; g < 2; g++)
#pragma unroll
        for (int dt = 0; dt < 4; dt++) o[g][dt] = (f32x4){0.f, 0.f, 0.f, 0.f};
    float mm[2] = {-1e30f, -1e30f}, ls[2] = {0.f, 0.f};

    auto stage = [&](int buf, int kt) {     // 4 gloads / thread
        bf16* lk = &smem[pair][buf][0];
        bf16* lv = &smem[pair][buf][2048];
#pragma unroll
        for (int i = 0; i < 2; i++) {
            int cc = 2 * qh + i;
            {
                int row = 8 * cc + (lane >> 3);
                int scc = (lane & 7) ^ (lane >> 3);
                gload16(&lk[cc * 512], kh + (size_t)(kt + row) * 64 + scc * 8);
            }
            {
                int row = 16 * cc + (lane >> 2);
                int su = (lane & 3) ^ ((lane >> 3) & 3);
                gload16(&lv[cc * 512], vh + (size_t)row * 2048 + kt + su * 8);
            }
        }
    };

    const f32x4 z = (f32x4){0.f, 0.f, 0.f, 0.f};
    auto compute = [&](int buf, bool diag) {
        const bf16* lk = &smem[pair][buf][0];
        const bf16* lv = &smem[pair][buf][2048];
        bf16x8 kf2[2][2];
#pragma unroll
        for (int t = 0; t < 2; t++)
#pragma unroll
            for (int h = 0; h < 2; h++) {
                int krow = 16 * t + l16;
                int koff = ((h * 64 + lg * 16) ^ ((l16 & 7) << 4)) >> 1;
                kf2[t][h] = *(const bf16x8*)(&lk[krow * 64 + koff]);
            }
        bf16x8 vf[4];
#pragma unroll
        for (int dt = 0; dt < 4; dt++) {
            int vrow = 16 * dt + l16;
            int rs = (l16 >> 1) & 3;
            const bf16* vb = &lv[vrow * 32];
            bf16x4 lo = *(const bf16x4*)(vb + (((lg >> 1) ^ rs) * 8 + (lg & 1) * 4));
            bf16x4 hi = *(const bf16x4*)(vb + (((2 + (lg >> 1)) ^ rs) * 8 + (lg & 1) * 4));
            vf[dt] = __builtin_shufflevector(lo, hi, 0, 1, 2, 3, 4, 5, 6, 7);
        }
        f32x4 sg[2][2];
#pragma unroll
        for (int g = 0; g < 2; g++)
#pragma unroll
            for (int t = 0; t < 2; t++) {
                f32x4 acc = MFMA16(kf2[t][0], qf[g][0], z);
                sg[g][t] = MFMA16(kf2[t][1], qf[g][1], acc);
            }
#pragma unroll
        for (int g = 0; g < 2; g++) {
            float p[8];
#pragma unroll
            for (int t = 0; t < 2; t++)
#pragma unroll
                for (int rr = 0; rr < 4; rr++) {
                    float v = sg[g][t][rr] * 0.125f;
                    if (diag && (16 * t + 4 * lg + rr > 16 * g + l16)) v = -1e30f;
                    p[4 * t + rr] = v;
                }
            float pm = p[0];
#pragma unroll
            for (int i = 1; i < 8; i++) pm = fmaxf(pm, p[i]);
            pm = fmaxf(pm, __shfl_xor(pm, 16, 64));
            pm = fmaxf(pm, __shfl_xor(pm, 32, 64));
            float mn = fmaxf(mm[g], pm);
            float al = __expf(mm[g] - mn);
#pragma unroll
            for (int dt = 0; dt < 4; dt++) o[g][dt] *= al;
            ls[g] *= al;
            mm[g] = mn;
            float ps = 0.f;
#pragma unroll
            for (int i = 0; i < 8; i++) {
                p[i] = __expf(p[i] - mn);
                ps += p[i];
            }
            ls[g] += ps;
            bf16x8 pf;
#pragma unroll
            for (int j = 0; j < 8; j++)
                pf[j] = __builtin_bit_cast(__bf16, __float2bfloat16(p[j]));
#pragma unroll
            for (int dt = 0; dt < 4; dt++) o[g][dt] = MFMA16(vf[dt], pf, o[g][dt]);
        }
    };

    const int base = pair ? (s + 1) : 0;
    const int niter = s + 1;
    stage(0, 32 * base);
    if (niter > 1) stage(1, 32 * (base + 1));
    int buf = 0;
    for (int i = 0; i < niter - 1; ++i) {
        asm volatile("s_waitcnt vmcnt(4)" ::: "memory");
        __builtin_amdgcn_s_barrier();
        __builtin_amdgcn_sched_barrier(0);
        if (i + 2 < niter) {
            int nb = buf + 2; if (nb >= 3) nb -= 3;
            stage(nb, 32 * (base + i + 2));
        }
        int kt = 32 * (base + i);
        if (kt <= q0w) compute(buf, kt == q0w);
        buf = (buf == 2) ? 0 : buf + 1;
    }
    asm volatile("s_waitcnt vmcnt(0)" ::: "memory");
    __builtin_amdgcn_s_barrier();
    __builtin_amdgcn_sched_barrier(0);
    {
        int kt = 32 * (base + niter - 1);
        if (kt <= q0w) compute(buf, kt == q0w);
    }

    __syncthreads();
    float* mg = (float*)&smem[0][0][0];
    if (pair == 1) {
        float* pp = mg + (qh * 64 + lane) * 36;
        pp[0] = mm[0]; pp[1] = mm[1]; pp[2] = ls[0]; pp[3] = ls[1];
#pragma unroll
        for (int g = 0; g < 2; g++)
#pragma unroll
            for (int dt = 0; dt < 4; dt++)
#pragma unroll
                for (int rr = 0; rr < 4; rr++)
                    pp[4 + g * 16 + dt * 4 + rr] = o[g][dt][rr];
    }
    __syncthreads();
    if (pair == 0) {
        const float* pp = mg + (qh * 64 + lane) * 36;
#pragma unroll
        for (int g = 0; g < 2; g++) {
            float m1 = pp[g], l1 = pp[2 + g];
            float mn = fmaxf(mm[g], m1);
            float a0 = __expf(mm[g] - mn);
            float a1 = __expf(m1 - mn);
            ls[g] = ls[g] * a0 + l1 * a1;
#pragma unroll
            for (int dt = 0; dt < 4; dt++)
#pragma unroll
                for (int rr = 0; rr < 4; rr++)
                    o[g][dt][rr] = o[g][dt][rr] * a0 + pp[4 + g * 16 + dt * 4 + rr] * a1;
        }
        const int b = bh >> 4, h = bh & 15;
#pragma unroll
        for (int g = 0; g < 2; g++) {
            float lt = ls[g];
            lt += __shfl_xor(lt, 16, 64);
            lt += __shfl_xor(lt, 32, 64);
            float inv = 1.f / lt;
            bf16* yp = y + ((size_t)(b * 2048 + q0w + 16 * g + l16)) * 1024 + h * 64 + 4 * lg;
#pragma unroll
            for (int dt = 0; dt < 4; dt++) {
                *(ushort4*)(yp + 16 * dt) = make_ushort4(
                    bb(o[g][dt][0] * inv), bb(o[g][dt][1] * inv),
                    bb(o[g][dt][2] * inv), bb(o[g][dt][3] * inv));
            }
        }
    }
}

// ---------- proj GEMM: R18 pipeline + XCD remap (1 N-block per XCD) ----------
__global__ __launch_bounds__(256) void k_gemm_proj(
    const bf16* __restrict__ A, const bf16* __restrict__ Bt,
    const float* __restrict__ bias, float* __restrict__ out) {
    __shared__ bf16 lA[3][128 * 32];
    __shared__ bf16 lB[3][128 * 32];
    const int tid = threadIdx.x;
    const int wave = tid >> 6, lane = tid & 63;
    const int wm = wave >> 1, wn = wave & 1;
    const int l16 = lane & 15, lg = lane >> 4;
    const int id = blockIdx.x;
    const int n0 = (id & 7) * 128;          // one N-block per XCD
    const int m0 = (id >> 3) * 128;

    f32x4 acc[4][4];
#pragma unroll
    for (int i = 0; i < 4; i++)
#pragma unroll
        for (int j = 0; j < 4; j++) acc[i][j] = (f32x4){0.f, 0.f, 0.f, 0.f};

    const int r = lane >> 2;
    const int sc = (lane & 3) ^ (r & 3);
    const bf16* gA = A + (size_t)(m0 + wave * 32 + r) * 1024 + sc * 8;
    const bf16* gB = Bt + (size_t)(n0 + wave * 32 + r) * 1024 + sc * 8;
    const int sw = (lg ^ (l16 & 3)) * 8;

    auto stage = [&](int buf, int k0) {
        bf16* sA = lA[buf] + wave * 1024;
        bf16* sB = lB[buf] + wave * 1024;
        gload16(sA, gA + k0);
        gload16(sA + 512, gA + (size_t)16 * 1024 + k0);
        gload16(sB, gB + k0);
        gload16(sB + 512, gB + (size_t)16 * 1024 + k0);
    };
    auto compute = [&](int buf) {
        bf16x8 af[4], bfr[4];
#pragma unroll
        for (int mi = 0; mi < 4; mi++)
            af[mi] = *(const bf16x8*)(lA[buf] + (wm * 64 + mi * 16 + l16) * 32 + sw);
#pragma unroll
        for (int nj = 0; nj < 4; nj++)
            bfr[nj] = *(const bf16x8*)(lB[buf] + (wn * 64 + nj * 16 + l16) * 32 + sw);
#pragma unroll
        for (int mi = 0; mi < 4; mi++)
#pragma unroll
            for (int nj = 0; nj < 4; nj++)
                acc[mi][nj] = MFMA16(af[mi], bfr[nj], acc[mi][nj]);
    };

    stage(0, 0);
    stage(1, 32);
    int buf = 0;
    for (int k0 = 0; k0 < 992; k0 += 32) {
        asm volatile("s_waitcnt vmcnt(4)" ::: "memory");
        __builtin_amdgcn_s_barrier();
        __builtin_amdgcn_sched_barrier(0);
        if (k0 + 64 < 1024) {
            int nb = buf + 2; if (nb >= 3) nb -= 3;
            stage(nb, k0 + 64);
        }
        compute(buf);
        buf = (buf == 2) ? 0 : buf + 1;
    }
    asm volatile("s_waitcnt vmcnt(0)" ::: "memory");
    __builtin_amdgcn_s_barrier();
    __builtin_amdgcn_sched_barrier(0);
    compute(buf);

#pragma unroll
    for (int mi = 0; mi < 4; mi++) {
        int mbase = m0 + wm * 64 + mi * 16 + lg * 4;
#pragma unroll
        for (int nj = 0; nj < 4; nj++) {
            int n = n0 + wn * 64 + nj * 16 + l16;
#pragma unroll
            for (int rr = 0; rr < 4; rr++) {
                out[(size_t)(mbase + rr) * 1024 + n] = acc[mi][nj][rr] + bias[n];
            }
        }
    }
}

// ---------- launch ----------
extern "C" void kernel_launch(void* const* d_in, const int* in_sizes, int n_in,
                              void* d_out, int out_size, void* d_ws, size_t ws_size,
                              hipStream_t stream) {
    const float* x = (const float*)d_in[0];
    const float* Wqkv = (const float*)d_in[1];
    const float* bqkv = (const float*)d_in[2];
    const float* Wproj = (const float*)d_in[3];
    const float* bproj = (const float*)d_in[4];
    float* out = (float*)d_out;

    char* ws = (char*)d_ws;
    bf16* xb = (bf16*)ws;      ws += (size_t)BT * C_ * 2;
    bf16* wqkvT = (bf16*)ws;   ws += (size_t)N3 * C_ * 2;
    bf16* wprojT = (bf16*)ws;  ws += (size_t)C_ * C_ * 2;
    bf16* qb = (bf16*)ws;      ws += (size_t)B_ * H_ * T_ * D_ * 2;
    bf16* kb = (bf16*)ws;      ws += (size_t)B_ * H_ * T_ * D_ * 2;
    bf16* vtb = (bf16*)ws;     ws += (size_t)B_ * H_ * T_ * D_ * 2;
    bf16* yb = (bf16*)ws;      ws += (size_t)BT * C_ * 2;
    float* ct = (float*)ws;    ws += (size_t)T_ * 32 * 4;
    float* st = (float*)ws;    ws += (size_t)T_ * 32 * 4;

    hipLaunchKernelGGL(k_prep, dim3(8448), dim3(256), 0, stream,
                       Wqkv, Wproj, x, wqkvT, wprojT, xb, ct, st);
    hipLaunchKernelGGL(k_gemm_qkv, dim3(768), dim3(256), 0, stream,
                       xb, wqkvT, bqkv, ct, st, qb, kb, vtb);
    hipLaunchKernelGGL(k_attn, dim3(32 * 32), dim3(256), 0, stream,
                       qb, kb, vtb, yb);
    hipLaunchKernelGGL(k_gemm_proj, dim3(256), dim3(256), 0, stream,
                       yb, wprojT, bproj, out);
}

// Round 23
// 127.364 us; speedup vs baseline: 1.0249x; 1.0249x over previous
//
#include <hip/hip_runtime.h>
#include <hip/hip_bf16.h>

typedef __hip_bfloat16 bf16;
typedef __attribute__((ext_vector_type(8))) __bf16 bf16x8;
typedef __attribute__((ext_vector_type(4))) __bf16 bf16x4;
typedef __attribute__((ext_vector_type(4))) float f32x4;
typedef unsigned short u16;

#define MFMA16(a, b, c) __builtin_amdgcn_mfma_f32_16x16x32_bf16((a), (b), (c), 0, 0, 0)

static constexpr int B_ = 2, T_ = 2048, C_ = 1024, H_ = 16, D_ = 64;
static constexpr int BT = B_ * T_;   // 4096
static constexpr int N3 = 3 * C_;    // 3072

__device__ __forceinline__ void gload16(void* lds, const void* g) {
    __builtin_amdgcn_global_load_lds(
        (const __attribute__((address_space(1))) unsigned int*)g,
        (__attribute__((address_space(3))) unsigned int*)lds, 16, 0, 0);
}

__device__ __forceinline__ u16 bb(float x) {
    return __builtin_bit_cast(u16, __float2bfloat16(x));
}

// ---------- fused prep kernel: transpose Wqkv | transpose Wproj | convert x | rope ----
__global__ __launch_bounds__(256) void k_prep(
    const float* __restrict__ Wqkv, const float* __restrict__ Wproj,
    const float* __restrict__ x,
    bf16* __restrict__ wqkvT, bf16* __restrict__ wprojT, bf16* __restrict__ xb,
    float* __restrict__ ct, float* __restrict__ st) {
    __shared__ float t[32][33];
    const int id = blockIdx.x;
    const int tid = threadIdx.x;
    if (id < 4096) {
        const float* src;
        bf16* dst;
        int N, bx, by;
        if (id < 3072) {
            src = Wqkv; dst = wqkvT; N = N3;
            bx = (id % 96) * 32; by = (id / 96) * 32;
        } else {
            src = Wproj; dst = wprojT; N = C_;
            int u = id - 3072;
            bx = (u % 32) * 32; by = (u / 32) * 32;
        }
        int tx = tid & 31, ty = tid >> 5;
#pragma unroll
        for (int i = 0; i < 32; i += 8)
            t[ty + i][tx] = src[(size_t)(by + ty + i) * N + bx + tx];
        __syncthreads();
#pragma unroll
        for (int i = 0; i < 32; i += 8)
            dst[(size_t)(bx + ty + i) * 1024 + by + tx] = __float2bfloat16(t[tx][ty + i]);
    } else if (id < 8192) {
        int i = (id - 4096) * 256 + tid;          // float4 index
        float4 v = reinterpret_cast<const float4*>(x)[i];
        xb[4 * i + 0] = __float2bfloat16(v.x);
        xb[4 * i + 1] = __float2bfloat16(v.y);
        xb[4 * i + 2] = __float2bfloat16(v.z);
        xb[4 * i + 3] = __float2bfloat16(v.w);
    } else {
        int i = (id - 8192) * 256 + tid;          // t*32 + f
        int tt = i >> 5, f = i & 31;
        float invf = exp2f(-(float)f * 0.4152410118609203f);  // 10000^(-f/32)
        float ang = (float)tt * invf;
        ct[i] = cosf(ang);
        st[i] = sinf(ang);
    }
}

// ---------- QKV GEMM: R14 config + 3-buffer counted-vmcnt pipeline (R18, proven) ----------
__global__ __launch_bounds__(256) void k_gemm_qkv(
    const bf16* __restrict__ A, const bf16* __restrict__ Bt,
    const float* __restrict__ bias,
    const float* __restrict__ ct, const float* __restrict__ st,
    bf16* __restrict__ q, bf16* __restrict__ kk, bf16* __restrict__ vt) {
    __shared__ bf16 lA[3][128 * 32];
    __shared__ bf16 lB[3][128 * 32];
    const int tid = threadIdx.x;
    const int wave = tid >> 6, lane = tid & 63;
    const int wm = wave >> 1, wn = wave & 1;
    const int l16 = lane & 15, lg = lane >> 4;
    const int m0 = blockIdx.y * 128, n0 = blockIdx.x * 128;

    f32x4 acc[4][4];
#pragma unroll
    for (int i = 0; i < 4; i++)
#pragma unroll
        for (int j = 0; j < 4; j++) acc[i][j] = (f32x4){0.f, 0.f, 0.f, 0.f};

    const int r = lane >> 2;
    const int sc = (lane & 3) ^ (r & 3);
    const bf16* gA = A + (size_t)(m0 + wave * 32 + r) * 1024 + sc * 8;
    const bf16* gB = Bt + (size_t)(n0 + wave * 32 + r) * 1024 + sc * 8;
    const int sw = (lg ^ (l16 & 3)) * 8;

    auto stage = [&](int buf, int k0) {
        bf16* sA = lA[buf] + wave * 1024;
        bf16* sB = lB[buf] + wave * 1024;
        gload16(sA, gA + k0);
        gload16(sA + 512, gA + (size_t)16 * 1024 + k0);
        gload16(sB, gB + k0);
        gload16(sB + 512, gB + (size_t)16 * 1024 + k0);
    };
    auto compute = [&](int buf) {
        bf16x8 af[4], bfr[4];
#pragma unroll
        for (int mi = 0; mi < 4; mi++)
            af[mi] = *(const bf16x8*)(lA[buf] + (wm * 64 + mi * 16 + l16) * 32 + sw);
#pragma unroll
        for (int nj = 0; nj < 4; nj++)
            bfr[nj] = *(const bf16x8*)(lB[buf] + (wn * 64 + nj * 16 + l16) * 32 + sw);
#pragma unroll
        for (int mi = 0; mi < 4; mi++)
#pragma unroll
            for (int nj = 0; nj < 4; nj++)
                acc[mi][nj] = MFMA16(af[mi], bfr[nj], acc[mi][nj]);
    };

    stage(0, 0);
    stage(1, 32);
    int buf = 0;
    for (int k0 = 0; k0 < 992; k0 += 32) {
        asm volatile("s_waitcnt vmcnt(4)" ::: "memory");
        __builtin_amdgcn_s_barrier();
        __builtin_amdgcn_sched_barrier(0);
        if (k0 + 64 < 1024) {
            int nb = buf + 2; if (nb >= 3) nb -= 3;
            stage(nb, k0 + 64);
        }
        compute(buf);
        buf = (buf == 2) ? 0 : buf + 1;
    }
    asm volatile("s_waitcnt vmcnt(0)" ::: "memory");
    __builtin_amdgcn_s_barrier();
    __builtin_amdgcn_sched_barrier(0);
    compute(buf);

    // epilogue: bias + RoPE + scatter
    const int b = m0 >> 11;
#pragma unroll
    for (int mi = 0; mi < 4; mi++) {
        int mbase = m0 + wm * 64 + mi * 16 + lg * 4;
#pragma unroll
        for (int nj = 0; nj < 4; nj++) {
            int n = n0 + wn * 64 + nj * 16 + l16;
            int which = n >> 10;
            int nq = n & 1023;
            int h = nq >> 6, d = nq & 63;
#pragma unroll
            for (int rr = 0; rr < 4; rr++) {
                int m = mbase + rr;
                int t = m & 2047;
                float v = acc[mi][nj][rr] + bias[n];
                if (which == 2) {
                    vt[((size_t)(b * 16 + h) * 64 + d) * 2048 + t] = __float2bfloat16(v);
                } else {
                    float pv = acc[mi][nj ^ 2][rr] + bias[n ^ 32];
                    float c = ct[t * 32 + (d & 31)];
                    float s = st[t * 32 + (d & 31)];
                    float rh = (d < 32) ? -pv : pv;
                    float o = v * c + rh * s;
                    bf16* dst = (which == 0) ? q : kk;
                    dst[((size_t)(b * 16 + h) * 2048 + t) * 64 + d] = __float2bfloat16(o);
                }
            }
        }
    }
}

// ---------- flash attention: split-K + 3-buffer counted-vmcnt pipeline (R21) ----------
__global__ __launch_bounds__(256, 3) void k_attn(
    const bf16* __restrict__ qg, const bf16* __restrict__ kg,
    const bf16* __restrict__ vtg, bf16* __restrict__ y) {
    __shared__ bf16 smem[2][3][4096];       // [pair][buf][K 2048 | V 2048] = 48 KB
    const int wv = threadIdx.x >> 6;
    const int pair = wv >> 1, qh = wv & 1;
    const int lane = threadIdx.x & 63;
    const int l16 = lane & 15, lg = lane >> 4;
    const int id = blockIdx.x;
    const int bh = id & 31;                 // id%8==bh%8 pins head to one XCD
    const int s = 31 - (id >> 5);           // strip (heavy first)
    const int q0w = s * 64 + 32 * qh;       // this wave's 32 q-rows
    const bf16* qh_p = qg + (size_t)bh * (2048 * 64);
    const bf16* kh = kg + (size_t)bh * (2048 * 64);
    const bf16* vh = vtg + (size_t)bh * (64 * 2048);

    bf16x8 qf[2][2];
#pragma unroll
    for (int g = 0; g < 2; g++)
#pragma unroll
        for (int h = 0; h < 2; h++)
            qf[g][h] = *(const bf16x8*)(qh_p + (size_t)(q0w + 16 * g + l16) * 64 + 32 * h + 8 * lg);

    f32x4 o[2][4];
#pragma unroll
    for (int g = 0; g < 2; g++)
#pragma unroll
        for (int dt = 0; dt < 4; dt++) o[g][dt] = (f32x4){0.f, 0.f, 0.f, 0.f};
    float mm[2] = {-1e30f, -1e30f}, ls[2] = {0.f, 0.f};

    auto stage = [&](int buf, int kt) {     // 4 gloads / thread
        bf16* lk = &smem[pair][buf][0];
        bf16* lv = &smem[pair][buf][2048];
#pragma unroll
        for (int i = 0; i < 2; i++) {
            int cc = 2 * qh + i;
            {
                int row = 8 * cc + (lane >> 3);
                int scc = (lane & 7) ^ (lane >> 3);
                gload16(&lk[cc * 512], kh + (size_t)(kt + row) * 64 + scc * 8);
            }
            {
                int row = 16 * cc + (lane >> 2);
                int su = (lane & 3) ^ ((lane >> 3) & 3);
                gload16(&lv[cc * 512], vh + (size_t)row * 2048 + kt + su * 8);
            }
        }
    };

    const f32x4 z = (f32x4){0.f, 0.f, 0.f, 0.f};
    auto compute = [&](int buf, bool diag) {
        const bf16* lk = &smem[pair][buf][0];
        const bf16* lv = &smem[pair][buf][2048];
        bf16x8 kf2[2][2];
#pragma unroll
        for (int t = 0; t < 2; t++)
#pragma unroll
            for (int h = 0; h < 2; h++) {
                int krow = 16 * t + l16;
                int koff = ((h * 64 + lg * 16) ^ ((l16 & 7) << 4)) >> 1;
                kf2[t][h] = *(const bf16x8*)(&lk[krow * 64 + koff]);
            }
        bf16x8 vf[4];
#pragma unroll
        for (int dt = 0; dt < 4; dt++) {
            int vrow = 16 * dt + l16;
            int rs = (l16 >> 1) & 3;
            const bf16* vb = &lv[vrow * 32];
            bf16x4 lo = *(const bf16x4*)(vb + (((lg >> 1) ^ rs) * 8 + (lg & 1) * 4));
            bf16x4 hi = *(const bf16x4*)(vb + (((2 + (lg >> 1)) ^ rs) * 8 + (lg & 1) * 4));
            vf[dt] = __builtin_shufflevector(lo, hi, 0, 1, 2, 3, 4, 5, 6, 7);
        }
        f32x4 sg[2][2];
#pragma unroll
        for (int g = 0; g < 2; g++)
#pragma unroll
            for (int t = 0; t < 2; t++) {
                f32x4 acc = MFMA16(kf2[t][0], qf[g][0], z);
                sg[g][t] = MFMA16(kf2[t][1], qf[g][1], acc);
            }
#pragma unroll
        for (int g = 0; g < 2; g++) {
            float p[8];
#pragma unroll
            for (int t = 0; t < 2; t++)
#pragma unroll
                for (int rr = 0; rr < 4; rr++) {
                    float v = sg[g][t][rr] * 0.125f;
                    if (diag && (16 * t + 4 * lg + rr > 16 * g + l16)) v = -1e30f;
                    p[4 * t + rr] = v;
                }
            float pm = p[0];
#pragma unroll
            for (int i = 1; i < 8; i++) pm = fmaxf(pm, p[i]);
            pm = fmaxf(pm, __shfl_xor(pm, 16, 64));
            pm = fmaxf(pm, __shfl_xor(pm, 32, 64));
            float mn = fmaxf(mm[g], pm);
            float al = __expf(mm[g] - mn);
#pragma unroll
            for (int dt = 0; dt < 4; dt++) o[g][dt] *= al;
            ls[g] *= al;
            mm[g] = mn;
            float ps = 0.f;
#pragma unroll
            for (int i = 0; i < 8; i++) {
                p[i] = __expf(p[i] - mn);
                ps += p[i];
            }
            ls[g] += ps;
            bf16x8 pf;
#pragma unroll
            for (int j = 0; j < 8; j++)
                pf[j] = __builtin_bit_cast(__bf16, __float2bfloat16(p[j]));
#pragma unroll
            for (int dt = 0; dt < 4; dt++) o[g][dt] = MFMA16(vf[dt], pf, o[g][dt]);
        }
    };

    const int base = pair ? (s + 1) : 0;
    const int niter = s + 1;
    stage(0, 32 * base);
    if (niter > 1) stage(1, 32 * (base + 1));
    int buf = 0;
    for (int i = 0; i < niter - 1; ++i) {
        asm volatile("s_waitcnt vmcnt(4)" ::: "memory");
        __builtin_amdgcn_s_barrier();
        __builtin_amdgcn_sched_barrier(0);
        if (i + 2 < niter) {
            int nb = buf + 2; if (nb >= 3) nb -= 3;
            stage(nb, 32 * (base + i + 2));
        }
        int kt = 32 * (base + i);
        if (kt <= q0w) compute(buf, kt == q0w);
        buf = (buf == 2) ? 0 : buf + 1;
    }
    asm volatile("s_waitcnt vmcnt(0)" ::: "memory");
    __builtin_amdgcn_s_barrier();
    __builtin_amdgcn_sched_barrier(0);
    {
        int kt = 32 * (base + niter - 1);
        if (kt <= q0w) compute(buf, kt == q0w);
    }

    __syncthreads();
    float* mg = (float*)&smem[0][0][0];
    if (pair == 1) {
        float* pp = mg + (qh * 64 + lane) * 36;
        pp[0] = mm[0]; pp[1] = mm[1]; pp[2] = ls[0]; pp[3] = ls[1];
#pragma unroll
        for (int g = 0; g < 2; g++)
#pragma unroll
            for (int dt = 0; dt < 4; dt++)
#pragma unroll
                for (int rr = 0; rr < 4; rr++)
                    pp[4 + g * 16 + dt * 4 + rr] = o[g][dt][rr];
    }
    __syncthreads();
    if (pair == 0) {
        const float* pp = mg + (qh * 64 + lane) * 36;
#pragma unroll
        for (int g = 0; g < 2; g++) {
            float m1 = pp[g], l1 = pp[2 + g];
            float mn = fmaxf(mm[g], m1);
            float a0 = __expf(mm[g] - mn);
            float a1 = __expf(m1 - mn);
            ls[g] = ls[g] * a0 + l1 * a1;
#pragma unroll
            for (int dt = 0; dt < 4; dt++)
#pragma unroll
                for (int rr = 0; rr < 4; rr++)
                    o[g][dt][rr] = o[g][dt][rr] * a0 + pp[4 + g * 16 + dt * 4 + rr] * a1;
        }
        const int b = bh >> 4, h = bh & 15;
#pragma unroll
        for (int g = 0; g < 2; g++) {
            float lt = ls[g];
            lt += __shfl_xor(lt, 16, 64);
            lt += __shfl_xor(lt, 32, 64);
            float inv = 1.f / lt;
            bf16* yp = y + ((size_t)(b * 2048 + q0w + 16 * g + l16)) * 1024 + h * 64 + 4 * lg;
#pragma unroll
            for (int dt = 0; dt < 4; dt++) {
                *(ushort4*)(yp + 16 * dt) = make_ushort4(
                    bb(o[g][dt][0] * inv), bb(o[g][dt][1] * inv),
                    bb(o[g][dt][2] * inv), bb(o[g][dt][3] * inv));
            }
        }
    }
}

// ---------- proj GEMM: R14 config + 3-buffer counted-vmcnt pipeline (R18) ----------
__global__ __launch_bounds__(256) void k_gemm_proj(
    const bf16* __restrict__ A, const bf16* __restrict__ Bt,
    const float* __restrict__ bias, float* __restrict__ out) {
    __shared__ bf16 lA[3][128 * 32];
    __shared__ bf16 lB[3][128 * 32];
    const int tid = threadIdx.x;
    const int wave = tid >> 6, lane = tid & 63;
    const int wm = wave >> 1, wn = wave & 1;
    const int l16 = lane & 15, lg = lane >> 4;
    const int m0 = blockIdx.y * 128, n0 = blockIdx.x * 128;

    f32x4 acc[4][4];
#pragma unroll
    for (int i = 0; i < 4; i++)
#pragma unroll
        for (int j = 0; j < 4; j++) acc[i][j] = (f32x4){0.f, 0.f, 0.f, 0.f};

    const int r = lane >> 2;
    const int sc = (lane & 3) ^ (r & 3);
    const bf16* gA = A + (size_t)(m0 + wave * 32 + r) * 1024 + sc * 8;
    const bf16* gB = Bt + (size_t)(n0 + wave * 32 + r) * 1024 + sc * 8;
    const int sw = (lg ^ (l16 & 3)) * 8;

    auto stage = [&](int buf, int k0) {
        bf16* sA = lA[buf] + wave * 1024;
        bf16* sB = lB[buf] + wave * 1024;
        gload16(sA, gA + k0);
        gload16(sA + 512, gA + (size_t)16 * 1024 + k0);
        gload16(sB, gB + k0);
        gload16(sB + 512, gB + (size_t)16 * 1024 + k0);
    };
    auto compute = [&](int buf) {
        bf16x8 af[4], bfr[4];
#pragma unroll
        for (int mi = 0; mi < 4; mi++)
            af[mi] = *(const bf16x8*)(lA[buf] + (wm * 64 + mi * 16 + l16) * 32 + sw);
#pragma unroll
        for (int nj = 0; nj < 4; nj++)
            bfr[nj] = *(const bf16x8*)(lB[buf] + (wn * 64 + nj * 16 + l16) * 32 + sw);
#pragma unroll
        for (int mi = 0; mi < 4; mi++)
#pragma unroll
            for (int nj = 0; nj < 4; nj++)
                acc[mi][nj] = MFMA16(af[mi], bfr[nj], acc[mi][nj]);
    };

    stage(0, 0);
    stage(1, 32);
    int buf = 0;
    for (int k0 = 0; k0 < 992; k0 += 32) {
        asm volatile("s_waitcnt vmcnt(4)" ::: "memory");
        __builtin_amdgcn_s_barrier();
        __builtin_amdgcn_sched_barrier(0);
        if (k0 + 64 < 1024) {
            int nb = buf + 2; if (nb >= 3) nb -= 3;
            stage(nb, k0 + 64);
        }
        compute(buf);
        buf = (buf == 2) ? 0 : buf + 1;
    }
    asm volatile("s_waitcnt vmcnt(0)" ::: "memory");
    __builtin_amdgcn_s_barrier();
    __builtin_amdgcn_sched_barrier(0);
    compute(buf);

#pragma unroll
    for (int mi = 0; mi < 4; mi++) {
        int mbase = m0 + wm * 64 + mi * 16 + lg * 4;
#pragma unroll
        for (int nj = 0; nj < 4; nj++) {
            int n = n0 + wn * 64 + nj * 16 + l16;
#pragma unroll
            for (int rr = 0; rr < 4; rr++) {
                out[(size_t)(mbase + rr) * 1024 + n] = acc[mi][nj][rr] + bias[n];
            }
        }
    }
}

// ---------- launch ----------
extern "C" void kernel_launch(void* const* d_in, const int* in_sizes, int n_in,
                              void* d_out, int out_size, void* d_ws, size_t ws_size,
                              hipStream_t stream) {
    const float* x = (const float*)d_in[0];
    const float* Wqkv = (const float*)d_in[1];
    const float* bqkv = (const float*)d_in[2];
    const float* Wproj = (const float*)d_in[3];
    const float* bproj = (const float*)d_in[4];
    float* out = (float*)d_out;

    char* ws = (char*)d_ws;
    bf16* xb = (bf16*)ws;      ws += (size_t)BT * C_ * 2;
    bf16* wqkvT = (bf16*)ws;   ws += (size_t)N3 * C_ * 2;
    bf16* wprojT = (bf16*)ws;  ws += (size_t)C_ * C_ * 2;
    bf16* qb = (bf16*)ws;      ws += (size_t)B_ * H_ * T_ * D_ * 2;
    bf16* kb = (bf16*)ws;      ws += (size_t)B_ * H_ * T_ * D_ * 2;
    bf16* vtb = (bf16*)ws;     ws += (size_t)B_ * H_ * T_ * D_ * 2;
    bf16* yb = (bf16*)ws;      ws += (size_t)BT * C_ * 2;
    float* ct = (float*)ws;    ws += (size_t)T_ * 32 * 4;
    float* st = (float*)ws;    ws += (size_t)T_ * 32 * 4;

    hipLaunchKernelGGL(k_prep, dim3(8448), dim3(256), 0, stream,
                       Wqkv, Wproj, x, wqkvT, wprojT, xb, ct, st);
    hipLaunchKernelGGL(k_gemm_qkv, dim3(N3 / 128, BT / 128), dim3(256), 0, stream,
                       xb, wqkvT, bqkv, ct, st, qb, kb, vtb);
    hipLaunchKernelGGL(k_attn, dim3(32 * 32), dim3(256), 0, stream,
                       qb, kb, vtb, yb);
    hipLaunchKernelGGL(k_gemm_proj, dim3(C_ / 128, BT / 128), dim3(256), 0, stream,
                       yb, wprojT, bproj, out);
}

// Round 24
// 126.364 us; speedup vs baseline: 1.0330x; 1.0079x over previous
//
#include <hip/hip_runtime.h>
#include <hip/hip_bf16.h>

typedef __hip_bfloat16 bf16;
typedef __attribute__((ext_vector_type(8))) __bf16 bf16x8;
typedef __attribute__((ext_vector_type(4))) __bf16 bf16x4;
typedef __attribute__((ext_vector_type(4))) float f32x4;
typedef unsigned short u16;

#define MFMA16(a, b, c) __builtin_amdgcn_mfma_f32_16x16x32_bf16((a), (b), (c), 0, 0, 0)

static constexpr int B_ = 2, T_ = 2048, C_ = 1024, H_ = 16, D_ = 64;
static constexpr int BT = B_ * T_;   // 4096
static constexpr int N3 = 3 * C_;    // 3072

__device__ __forceinline__ void gload16(void* lds, const void* g) {
    __builtin_amdgcn_global_load_lds(
        (const __attribute__((address_space(1))) unsigned int*)g,
        (__attribute__((address_space(3))) unsigned int*)lds, 16, 0, 0);
}

__device__ __forceinline__ u16 bb(float x) {
    return __builtin_bit_cast(u16, __float2bfloat16(x));
}

// ---------- fused prep kernel: transpose Wqkv | transpose Wproj | convert x | rope ----
__global__ __launch_bounds__(256) void k_prep(
    const float* __restrict__ Wqkv, const float* __restrict__ Wproj,
    const float* __restrict__ x,
    bf16* __restrict__ wqkvT, bf16* __restrict__ wprojT, bf16* __restrict__ xb,
    float* __restrict__ ct, float* __restrict__ st) {
    __shared__ float t[32][33];
    const int id = blockIdx.x;
    const int tid = threadIdx.x;
    if (id < 4096) {
        const float* src;
        bf16* dst;
        int N, bx, by;
        if (id < 3072) {
            src = Wqkv; dst = wqkvT; N = N3;
            bx = (id % 96) * 32; by = (id / 96) * 32;
        } else {
            src = Wproj; dst = wprojT; N = C_;
            int u = id - 3072;
            bx = (u % 32) * 32; by = (u / 32) * 32;
        }
        int tx = tid & 31, ty = tid >> 5;
#pragma unroll
        for (int i = 0; i < 32; i += 8)
            t[ty + i][tx] = src[(size_t)(by + ty + i) * N + bx + tx];
        __syncthreads();
#pragma unroll
        for (int i = 0; i < 32; i += 8)
            dst[(size_t)(bx + ty + i) * 1024 + by + tx] = __float2bfloat16(t[tx][ty + i]);
    } else if (id < 8192) {
        int i = (id - 4096) * 256 + tid;          // float4 index
        float4 v = reinterpret_cast<const float4*>(x)[i];
        xb[4 * i + 0] = __float2bfloat16(v.x);
        xb[4 * i + 1] = __float2bfloat16(v.y);
        xb[4 * i + 2] = __float2bfloat16(v.z);
        xb[4 * i + 3] = __float2bfloat16(v.w);
    } else {
        int i = (id - 8192) * 256 + tid;          // t*32 + f
        int tt = i >> 5, f = i & 31;
        float invf = exp2f(-(float)f * 0.4152410118609203f);  // 10000^(-f/32)
        float ang = (float)tt * invf;
        ct[i] = cosf(ang);
        st[i] = sinf(ang);
    }
}

// ---------- QKV GEMM: R14 config + 3-buffer counted-vmcnt pipeline (R18, proven) ----------
__global__ __launch_bounds__(256) void k_gemm_qkv(
    const bf16* __restrict__ A, const bf16* __restrict__ Bt,
    const float* __restrict__ bias,
    const float* __restrict__ ct, const float* __restrict__ st,
    bf16* __restrict__ q, bf16* __restrict__ kk, bf16* __restrict__ vt) {
    __shared__ bf16 lA[3][128 * 32];
    __shared__ bf16 lB[3][128 * 32];
    const int tid = threadIdx.x;
    const int wave = tid >> 6, lane = tid & 63;
    const int wm = wave >> 1, wn = wave & 1;
    const int l16 = lane & 15, lg = lane >> 4;
    const int m0 = blockIdx.y * 128, n0 = blockIdx.x * 128;

    f32x4 acc[4][4];
#pragma unroll
    for (int i = 0; i < 4; i++)
#pragma unroll
        for (int j = 0; j < 4; j++) acc[i][j] = (f32x4){0.f, 0.f, 0.f, 0.f};

    const int r = lane >> 2;
    const int sc = (lane & 3) ^ (r & 3);
    const bf16* gA = A + (size_t)(m0 + wave * 32 + r) * 1024 + sc * 8;
    const bf16* gB = Bt + (size_t)(n0 + wave * 32 + r) * 1024 + sc * 8;
    const int sw = (lg ^ (l16 & 3)) * 8;

    auto stage = [&](int buf, int k0) {
        bf16* sA = lA[buf] + wave * 1024;
        bf16* sB = lB[buf] + wave * 1024;
        gload16(sA, gA + k0);
        gload16(sA + 512, gA + (size_t)16 * 1024 + k0);
        gload16(sB, gB + k0);
        gload16(sB + 512, gB + (size_t)16 * 1024 + k0);
    };
    auto compute = [&](int buf) {
        bf16x8 af[4], bfr[4];
#pragma unroll
        for (int mi = 0; mi < 4; mi++)
            af[mi] = *(const bf16x8*)(lA[buf] + (wm * 64 + mi * 16 + l16) * 32 + sw);
#pragma unroll
        for (int nj = 0; nj < 4; nj++)
            bfr[nj] = *(const bf16x8*)(lB[buf] + (wn * 64 + nj * 16 + l16) * 32 + sw);
#pragma unroll
        for (int mi = 0; mi < 4; mi++)
#pragma unroll
            for (int nj = 0; nj < 4; nj++)
                acc[mi][nj] = MFMA16(af[mi], bfr[nj], acc[mi][nj]);
    };

    stage(0, 0);
    stage(1, 32);
    int buf = 0;
    for (int k0 = 0; k0 < 992; k0 += 32) {
        asm volatile("s_waitcnt vmcnt(4)" ::: "memory");
        __builtin_amdgcn_s_barrier();
        __builtin_amdgcn_sched_barrier(0);
        if (k0 + 64 < 1024) {
            int nb = buf + 2; if (nb >= 3) nb -= 3;
            stage(nb, k0 + 64);
        }
        compute(buf);
        buf = (buf == 2) ? 0 : buf + 1;
    }
    asm volatile("s_waitcnt vmcnt(0)" ::: "memory");
    __builtin_amdgcn_s_barrier();
    __builtin_amdgcn_sched_barrier(0);
    compute(buf);

    // epilogue: bias + RoPE + scatter
    const int b = m0 >> 11;
#pragma unroll
    for (int mi = 0; mi < 4; mi++) {
        int mbase = m0 + wm * 64 + mi * 16 + lg * 4;
#pragma unroll
        for (int nj = 0; nj < 4; nj++) {
            int n = n0 + wn * 64 + nj * 16 + l16;
            int which = n >> 10;
            int nq = n & 1023;
            int h = nq >> 6, d = nq & 63;
#pragma unroll
            for (int rr = 0; rr < 4; rr++) {
                int m = mbase + rr;
                int t = m & 2047;
                float v = acc[mi][nj][rr] + bias[n];
                if (which == 2) {
                    vt[((size_t)(b * 16 + h) * 64 + d) * 2048 + t] = __float2bfloat16(v);
                } else {
                    float pv = acc[mi][nj ^ 2][rr] + bias[n ^ 32];
                    float c = ct[t * 32 + (d & 31)];
                    float s = st[t * 32 + (d & 31)];
                    float rh = (d < 32) ? -pv : pv;
                    float o = v * c + rh * s;
                    bf16* dst = (which == 0) ? q : kk;
                    dst[((size_t)(b * 16 + h) * 2048 + t) * 64 + d] = __float2bfloat16(o);
                }
            }
        }
    }
}

// ---------- flash attention: split-K + 2-buffer counted-vmcnt (32 KB, 2 barriers/iter) ----
// Per iter: vmcnt(4) [stage(i) done; stage(i+1) in flight] -> s_barrier ->
// compute(i&1) -> s_barrier -> stage(i+2 -> buf i&1). No vmcnt drain in loop;
// 32 KB LDS restores 4 resident blocks/CU (R21's 48 KB capped at 3).
__global__ __launch_bounds__(256, 4) void k_attn(
    const bf16* __restrict__ qg, const bf16* __restrict__ kg,
    const bf16* __restrict__ vtg, bf16* __restrict__ y) {
    __shared__ bf16 smem[2][2][4096];       // [pair][buf][K 2048 | V 2048] = 32 KB
    const int wv = threadIdx.x >> 6;
    const int pair = wv >> 1, qh = wv & 1;
    const int lane = threadIdx.x & 63;
    const int l16 = lane & 15, lg = lane >> 4;
    const int id = blockIdx.x;
    const int bh = id & 31;                 // id%8==bh%8 pins head to one XCD
    const int s = 31 - (id >> 5);           // strip (heavy first)
    const int q0w = s * 64 + 32 * qh;       // this wave's 32 q-rows
    const bf16* qh_p = qg + (size_t)bh * (2048 * 64);
    const bf16* kh = kg + (size_t)bh * (2048 * 64);
    const bf16* vh = vtg + (size_t)bh * (64 * 2048);

    bf16x8 qf[2][2];
#pragma unroll
    for (int g = 0; g < 2; g++)
#pragma unroll
        for (int h = 0; h < 2; h++)
            qf[g][h] = *(const bf16x8*)(qh_p + (size_t)(q0w + 16 * g + l16) * 64 + 32 * h + 8 * lg);

    f32x4 o[2][4];
#pragma unroll
    for (int g = 0; g < 2; g++)
#pragma unroll
        for (int dt = 0; dt < 4; dt++) o[g][dt] = (f32x4){0.f, 0.f, 0.f, 0.f};
    float mm[2] = {-1e30f, -1e30f}, ls[2] = {0.f, 0.f};

    auto stage = [&](int buf, int kt) {     // 4 gloads / thread
        bf16* lk = &smem[pair][buf][0];
        bf16* lv = &smem[pair][buf][2048];
#pragma unroll
        for (int i = 0; i < 2; i++) {
            int cc = 2 * qh + i;
            {
                int row = 8 * cc + (lane >> 3);
                int scc = (lane & 7) ^ (lane >> 3);
                gload16(&lk[cc * 512], kh + (size_t)(kt + row) * 64 + scc * 8);
            }
            {
                int row = 16 * cc + (lane >> 2);
                int su = (lane & 3) ^ ((lane >> 3) & 3);
                gload16(&lv[cc * 512], vh + (size_t)row * 2048 + kt + su * 8);
            }
        }
    };

    const f32x4 z = (f32x4){0.f, 0.f, 0.f, 0.f};
    auto compute = [&](int buf, bool diag) {
        const bf16* lk = &smem[pair][buf][0];
        const bf16* lv = &smem[pair][buf][2048];
        bf16x8 kf2[2][2];
#pragma unroll
        for (int t = 0; t < 2; t++)
#pragma unroll
            for (int h = 0; h < 2; h++) {
                int krow = 16 * t + l16;
                int koff = ((h * 64 + lg * 16) ^ ((l16 & 7) << 4)) >> 1;
                kf2[t][h] = *(const bf16x8*)(&lk[krow * 64 + koff]);
            }
        bf16x8 vf[4];
#pragma unroll
        for (int dt = 0; dt < 4; dt++) {
            int vrow = 16 * dt + l16;
            int rs = (l16 >> 1) & 3;
            const bf16* vb = &lv[vrow * 32];
            bf16x4 lo = *(const bf16x4*)(vb + (((lg >> 1) ^ rs) * 8 + (lg & 1) * 4));
            bf16x4 hi = *(const bf16x4*)(vb + (((2 + (lg >> 1)) ^ rs) * 8 + (lg & 1) * 4));
            vf[dt] = __builtin_shufflevector(lo, hi, 0, 1, 2, 3, 4, 5, 6, 7);
        }
        f32x4 sg[2][2];
#pragma unroll
        for (int g = 0; g < 2; g++)
#pragma unroll
            for (int t = 0; t < 2; t++) {
                f32x4 acc = MFMA16(kf2[t][0], qf[g][0], z);
                sg[g][t] = MFMA16(kf2[t][1], qf[g][1], acc);
            }
#pragma unroll
        for (int g = 0; g < 2; g++) {
            float p[8];
#pragma unroll
            for (int t = 0; t < 2; t++)
#pragma unroll
                for (int rr = 0; rr < 4; rr++) {
                    float v = sg[g][t][rr] * 0.125f;
                    if (diag && (16 * t + 4 * lg + rr > 16 * g + l16)) v = -1e30f;
                    p[4 * t + rr] = v;
                }
            float pm = p[0];
#pragma unroll
            for (int i = 1; i < 8; i++) pm = fmaxf(pm, p[i]);
            pm = fmaxf(pm, __shfl_xor(pm, 16, 64));
            pm = fmaxf(pm, __shfl_xor(pm, 32, 64));
            float mn = fmaxf(mm[g], pm);
            float al = __expf(mm[g] - mn);
#pragma unroll
            for (int dt = 0; dt < 4; dt++) o[g][dt] *= al;
            ls[g] *= al;
            mm[g] = mn;
            float ps = 0.f;
#pragma unroll
            for (int i = 0; i < 8; i++) {
                p[i] = __expf(p[i] - mn);
                ps += p[i];
            }
            ls[g] += ps;
            bf16x8 pf;
#pragma unroll
            for (int j = 0; j < 8; j++)
                pf[j] = __builtin_bit_cast(__bf16, __float2bfloat16(p[j]));
#pragma unroll
            for (int dt = 0; dt < 4; dt++) o[g][dt] = MFMA16(vf[dt], pf, o[g][dt]);
        }
    };

    // pair0: tiles 0..s ; pair1: tiles s+1..2s+1 (niter = s+1 each -> equal barriers)
    const int base = pair ? (s + 1) : 0;
    const int niter = s + 1;
    stage(0, 32 * base);
    if (niter > 1) stage(1, 32 * (base + 1));
    for (int i = 0; i < niter; ++i) {
        if (i + 1 < niter) asm volatile("s_waitcnt vmcnt(4)" ::: "memory");
        else               asm volatile("s_waitcnt vmcnt(0)" ::: "memory");
        __builtin_amdgcn_s_barrier();
        __builtin_amdgcn_sched_barrier(0);
        int kt = 32 * (base + i);
        if (kt <= q0w) compute(i & 1, kt == q0w);
        __builtin_amdgcn_s_barrier();
        __builtin_amdgcn_sched_barrier(0);
        if (i + 2 < niter) stage(i & 1, 32 * (base + i + 2));
    }

    // ---- exact split-K merge (pair1 -> pair0) via LDS ----
    __syncthreads();
    float* mg = (float*)&smem[0][0][0];
    if (pair == 1) {
        float* pp = mg + (qh * 64 + lane) * 36;
        pp[0] = mm[0]; pp[1] = mm[1]; pp[2] = ls[0]; pp[3] = ls[1];
#pragma unroll
        for (int g = 0; g < 2; g++)
#pragma unroll
            for (int dt = 0; dt < 4; dt++)
#pragma unroll
                for (int rr = 0; rr < 4; rr++)
                    pp[4 + g * 16 + dt * 4 + rr] = o[g][dt][rr];
    }
    __syncthreads();
    if (pair == 0) {
        const float* pp = mg + (qh * 64 + lane) * 36;
#pragma unroll
        for (int g = 0; g < 2; g++) {
            float m1 = pp[g], l1 = pp[2 + g];
            float mn = fmaxf(mm[g], m1);
            float a0 = __expf(mm[g] - mn);
            float a1 = __expf(m1 - mn);
            ls[g] = ls[g] * a0 + l1 * a1;
#pragma unroll
            for (int dt = 0; dt < 4; dt++)
#pragma unroll
                for (int rr = 0; rr < 4; rr++)
                    o[g][dt][rr] = o[g][dt][rr] * a0 + pp[4 + g * 16 + dt * 4 + rr] * a1;
        }
        const int b = bh >> 4, h = bh & 15;
#pragma unroll
        for (int g = 0; g < 2; g++) {
            float lt = ls[g];
            lt += __shfl_xor(lt, 16, 64);
            lt += __shfl_xor(lt, 32, 64);
            float inv = 1.f / lt;
            bf16* yp = y + ((size_t)(b * 2048 + q0w + 16 * g + l16)) * 1024 + h * 64 + 4 * lg;
#pragma unroll
            for (int dt = 0; dt < 4; dt++) {
                *(ushort4*)(yp + 16 * dt) = make_ushort4(
                    bb(o[g][dt][0] * inv), bb(o[g][dt][1] * inv),
                    bb(o[g][dt][2] * inv), bb(o[g][dt][3] * inv));
            }
        }
    }
}

// ---------- proj GEMM: R14 config + 3-buffer counted-vmcnt pipeline (R18) ----------
__global__ __launch_bounds__(256) void k_gemm_proj(
    const bf16* __restrict__ A, const bf16* __restrict__ Bt,
    const float* __restrict__ bias, float* __restrict__ out) {
    __shared__ bf16 lA[3][128 * 32];
    __shared__ bf16 lB[3][128 * 32];
    const int tid = threadIdx.x;
    const int wave = tid >> 6, lane = tid & 63;
    const int wm = wave >> 1, wn = wave & 1;
    const int l16 = lane & 15, lg = lane >> 4;
    const int m0 = blockIdx.y * 128, n0 = blockIdx.x * 128;

    f32x4 acc[4][4];
#pragma unroll
    for (int i = 0; i < 4; i++)
#pragma unroll
        for (int j = 0; j < 4; j++) acc[i][j] = (f32x4){0.f, 0.f, 0.f, 0.f};

    const int r = lane >> 2;
    const int sc = (lane & 3) ^ (r & 3);
    const bf16* gA = A + (size_t)(m0 + wave * 32 + r) * 1024 + sc * 8;
    const bf16* gB = Bt + (size_t)(n0 + wave * 32 + r) * 1024 + sc * 8;
    const int sw = (lg ^ (l16 & 3)) * 8;

    auto stage = [&](int buf, int k0) {
        bf16* sA = lA[buf] + wave * 1024;
        bf16* sB = lB[buf] + wave * 1024;
        gload16(sA, gA + k0);
        gload16(sA + 512, gA + (size_t)16 * 1024 + k0);
        gload16(sB, gB + k0);
        gload16(sB + 512, gB + (size_t)16 * 1024 + k0);
    };
    auto compute = [&](int buf) {
        bf16x8 af[4], bfr[4];
#pragma unroll
        for (int mi = 0; mi < 4; mi++)
            af[mi] = *(const bf16x8*)(lA[buf] + (wm * 64 + mi * 16 + l16) * 32 + sw);
#pragma unroll
        for (int nj = 0; nj < 4; nj++)
            bfr[nj] = *(const bf16x8*)(lB[buf] + (wn * 64 + nj * 16 + l16) * 32 + sw);
#pragma unroll
        for (int mi = 0; mi < 4; mi++)
#pragma unroll
            for (int nj = 0; nj < 4; nj++)
                acc[mi][nj] = MFMA16(af[mi], bfr[nj], acc[mi][nj]);
    };

    stage(0, 0);
    stage(1, 32);
    int buf = 0;
    for (int k0 = 0; k0 < 992; k0 += 32) {
        asm volatile("s_waitcnt vmcnt(4)" ::: "memory");
        __builtin_amdgcn_s_barrier();
        __builtin_amdgcn_sched_barrier(0);
        if (k0 + 64 < 1024) {
            int nb = buf + 2; if (nb >= 3) nb -= 3;
            stage(nb, k0 + 64);
        }
        compute(buf);
        buf = (buf == 2) ? 0 : buf + 1;
    }
    asm volatile("s_waitcnt vmcnt(0)" ::: "memory");
    __builtin_amdgcn_s_barrier();
    __builtin_amdgcn_sched_barrier(0);
    compute(buf);

#pragma unroll
    for (int mi = 0; mi < 4; mi++) {
        int mbase = m0 + wm * 64 + mi * 16 + lg * 4;
#pragma unroll
        for (int nj = 0; nj < 4; nj++) {
            int n = n0 + wn * 64 + nj * 16 + l16;
#pragma unroll
            for (int rr = 0; rr < 4; rr++) {
                out[(size_t)(mbase + rr) * 1024 + n] = acc[mi][nj][rr] + bias[n];
            }
        }
    }
}

// ---------- launch ----------
extern "C" void kernel_launch(void* const* d_in, const int* in_sizes, int n_in,
                              void* d_out, int out_size, void* d_ws, size_t ws_size,
                              hipStream_t stream) {
    const float* x = (const float*)d_in[0];
    const float* Wqkv = (const float*)d_in[1];
    const float* bqkv = (const float*)d_in[2];
    const float* Wproj = (const float*)d_in[3];
    const float* bproj = (const float*)d_in[4];
    float* out = (float*)d_out;

    char* ws = (char*)d_ws;
    bf16* xb = (bf16*)ws;      ws += (size_t)BT * C_ * 2;
    bf16* wqkvT = (bf16*)ws;   ws += (size_t)N3 * C_ * 2;
    bf16* wprojT = (bf16*)ws;  ws += (size_t)C_ * C_ * 2;
    bf16* qb = (bf16*)ws;      ws += (size_t)B_ * H_ * T_ * D_ * 2;
    bf16* kb = (bf16*)ws;      ws += (size_t)B_ * H_ * T_ * D_ * 2;
    bf16* vtb = (bf16*)ws;     ws += (size_t)B_ * H_ * T_ * D_ * 2;
    bf16* yb = (bf16*)ws;      ws += (size_t)BT * C_ * 2;
    float* ct = (float*)ws;    ws += (size_t)T_ * 32 * 4;
    float* st = (float*)ws;    ws += (size_t)T_ * 32 * 4;

    hipLaunchKernelGGL(k_prep, dim3(8448), dim3(256), 0, stream,
                       Wqkv, Wproj, x, wqkvT, wprojT, xb, ct, st);
    hipLaunchKernelGGL(k_gemm_qkv, dim3(N3 / 128, BT / 128), dim3(256), 0, stream,
                       xb, wqkvT, bqkv, ct, st, qb, kb, vtb);
    hipLaunchKernelGGL(k_attn, dim3(32 * 32), dim3(256), 0, stream,
                       qb, kb, vtb, yb);
    hipLaunchKernelGGL(k_gemm_proj, dim3(C_ / 128, BT / 128), dim3(256), 0, stream,
                       yb, wprojT, bproj, out);
}